// Round 8
// baseline (1049.219 us; speedup 1.0000x reference)
//
#include <hip/hip_runtime.h>
#include <hip/hip_bf16.h>

#define D_MODEL   640
#define D_INNER   1280
#define D_STATE   34
#define D_CONV    4
#define DT_RANK   40
#define BATCH     2
#define SEQ       2048
#define XDBL_W    (DT_RANK + 2 * D_STATE)   // 108
#define M_TOTAL   (BATCH * SEQ)             // 4096

// ---------------------------------------------------------------------------
// Big-tile f32 GEMM: C[M,N] = A.B^T, A is [M,K] (LAYA=0) or [K,M] (LAYA=1),
// B is [N,K]. BM=128, BN_ in {64,128}, BK=16, 256 threads, 8x(BN_/16) microtile.
// MODE: 0 = none, 1 = silu(v), 2 = softplus(v + bias[gm])
// ---------------------------------------------------------------------------
template<int LAYA, int MODE, int BN_>
__global__ __launch_bounds__(256) void gemm128(
    const float* __restrict__ A, const float* __restrict__ B,
    float* __restrict__ C, int M, int N, int K, int lda, int ldb, int ldc,
    const float* __restrict__ bias)
{
    constexpr int BM_ = 128, BKt = 16;
    constexpr int TN = BN_ / 16;
    __shared__ float As[BKt][BM_ + 4];
    __shared__ float Bs[BKt][BN_ + 4];

    const int tid = threadIdx.x;
    const int m0 = blockIdx.y * BM_;
    const int n0 = blockIdx.x * BN_;
    const int tx = tid & 15;          // n
    const int ty = tid >> 4;          // m

    float acc[8][TN] = {};

    for (int k0 = 0; k0 < K; k0 += BKt) {
        // ---- stage A tile (128 x 16)
        if (LAYA == 0) {
            #pragma unroll
            for (int ci = 0; ci < (BM_ * BKt) / (256 * 4); ++ci) {
                int f = tid + ci * 256;
                int r = f >> 2, koff = (f & 3) << 2;
                int gm = m0 + r, gk = k0 + koff;
                float4 v;
                if (gm < M && gk + 3 < K) {
                    v = *reinterpret_cast<const float4*>(&A[(long)gm * lda + gk]);
                } else {
                    v.x = (gm < M && gk + 0 < K) ? A[(long)gm * lda + gk + 0] : 0.f;
                    v.y = (gm < M && gk + 1 < K) ? A[(long)gm * lda + gk + 1] : 0.f;
                    v.z = (gm < M && gk + 2 < K) ? A[(long)gm * lda + gk + 2] : 0.f;
                    v.w = (gm < M && gk + 3 < K) ? A[(long)gm * lda + gk + 3] : 0.f;
                }
                As[koff + 0][r] = v.x; As[koff + 1][r] = v.y;
                As[koff + 2][r] = v.z; As[koff + 3][r] = v.w;
            }
        } else {
            #pragma unroll
            for (int ci = 0; ci < (BM_ * BKt) / (256 * 4); ++ci) {
                int f = tid + ci * 256;
                int c = f >> 5;                 // 32 float4 per k-row
                int moff = (f & 31) << 2;
                int gk = k0 + c;
                float4 v = {0.f, 0.f, 0.f, 0.f};
                if (gk < K && m0 + moff < M)
                    v = *reinterpret_cast<const float4*>(&A[(long)gk * lda + m0 + moff]);
                *reinterpret_cast<float4*>(&As[c][moff]) = v;
            }
        }
        // ---- stage B tile (BN_ x 16), k-contiguous
        #pragma unroll
        for (int ci = 0; ci < (BN_ * BKt) / (256 * 4); ++ci) {
            int f = tid + ci * 256;
            int r = f >> 2, koff = (f & 3) << 2;
            int gn = n0 + r, gk = k0 + koff;
            float4 v;
            if (gn < N && gk + 3 < K) {
                v = *reinterpret_cast<const float4*>(&B[(long)gn * ldb + gk]);
            } else {
                v.x = (gn < N && gk + 0 < K) ? B[(long)gn * ldb + gk + 0] : 0.f;
                v.y = (gn < N && gk + 1 < K) ? B[(long)gn * ldb + gk + 1] : 0.f;
                v.z = (gn < N && gk + 2 < K) ? B[(long)gn * ldb + gk + 2] : 0.f;
                v.w = (gn < N && gk + 3 < K) ? B[(long)gn * ldb + gk + 3] : 0.f;
            }
            Bs[koff + 0][r] = v.x; Bs[koff + 1][r] = v.y;
            Bs[koff + 2][r] = v.z; Bs[koff + 3][r] = v.w;
        }
        __syncthreads();

        #pragma unroll
        for (int k = 0; k < BKt; ++k) {
            float a_[8], b_[TN];
            *reinterpret_cast<float4*>(&a_[0]) =
                *reinterpret_cast<const float4*>(&As[k][ty * 8]);
            *reinterpret_cast<float4*>(&a_[4]) =
                *reinterpret_cast<const float4*>(&As[k][ty * 8 + 4]);
            #pragma unroll
            for (int j4 = 0; j4 < TN; j4 += 4)
                *reinterpret_cast<float4*>(&b_[j4]) =
                    *reinterpret_cast<const float4*>(&Bs[k][tx * TN + j4]);
            #pragma unroll
            for (int i = 0; i < 8; ++i)
                #pragma unroll
                for (int j = 0; j < TN; ++j)
                    acc[i][j] = fmaf(a_[i], b_[j], acc[i][j]);
        }
        __syncthreads();
    }

    // ---- epilogue (float4 stores; our launch dims are exact multiples)
    #pragma unroll
    for (int i = 0; i < 8; ++i) {
        int gm = m0 + ty * 8 + i;
        if (gm >= M) continue;
        float bi = (MODE == 2) ? bias[gm] : 0.0f;
        #pragma unroll
        for (int j4 = 0; j4 < TN; j4 += 4) {
            int gn = n0 + tx * TN + j4;
            float vv[4];
            #pragma unroll
            for (int j = 0; j < 4; ++j) {
                float v = acc[i][j4 + j];
                if (MODE == 1) v = v * (1.0f / (1.0f + __expf(-v)));
                if (MODE == 2) {
                    v += bi;
                    v = (v > 15.0f) ? v : log1pf(__expf(v));
                }
                vv[j] = v;
            }
            if (gn + 3 < N) {
                *reinterpret_cast<float4*>(&C[(long)gm * ldc + gn]) =
                    *reinterpret_cast<float4*>(vv);
            } else {
                for (int j = 0; j < 4; ++j)
                    if (gn + j < N) C[(long)gm * ldc + gn + j] = vv[j];
            }
        }
    }
}

// ---------------------------------------------------------------------------
// Small-N f32 GEMM (kept for the thin x_dbl projection, N=108).
// ---------------------------------------------------------------------------
#define BM 64
#define BN 64
#define BK 16

template<int LAYA, int MODE>
__global__ __launch_bounds__(256) void gemm_tn(
    const float* __restrict__ A, const float* __restrict__ B,
    float* __restrict__ C, int M, int N, int K, int lda, int ldb, int ldc,
    const float* __restrict__ bias)
{
    __shared__ float As[BK][BM + 4];
    __shared__ float Bs[BK][BN + 4];

    const int tid = threadIdx.x;
    const int m0 = blockIdx.y * BM;
    const int n0 = blockIdx.x * BN;
    const int tx = tid & 15;
    const int ty = tid >> 4;

    float acc[4][4] = {};

    for (int k0 = 0; k0 < K; k0 += BK) {
        #pragma unroll
        for (int i = 0; i < 4; ++i) {
            int idx = tid + i * 256;
            if (LAYA == 0) {
                int r = idx >> 4;
                int c = idx & 15;
                As[c][r] = (m0 + r < M && k0 + c < K)
                         ? A[(long)(m0 + r) * lda + (k0 + c)] : 0.0f;
            } else {
                int c = idx >> 6;
                int r = idx & 63;
                As[c][r] = (m0 + r < M && k0 + c < K)
                         ? A[(long)(k0 + c) * lda + (m0 + r)] : 0.0f;
            }
            int rb = idx >> 4;
            int cb = idx & 15;
            Bs[cb][rb] = (n0 + rb < N && k0 + cb < K)
                       ? B[(long)(n0 + rb) * ldb + (k0 + cb)] : 0.0f;
        }
        __syncthreads();

        #pragma unroll
        for (int k = 0; k < BK; ++k) {
            const float4 a4 = *reinterpret_cast<const float4*>(&As[k][ty * 4]);
            const float4 b4 = *reinterpret_cast<const float4*>(&Bs[k][tx * 4]);
            const float a_[4] = {a4.x, a4.y, a4.z, a4.w};
            const float b_[4] = {b4.x, b4.y, b4.z, b4.w};
            #pragma unroll
            for (int i = 0; i < 4; ++i)
                #pragma unroll
                for (int j = 0; j < 4; ++j)
                    acc[i][j] = fmaf(a_[i], b_[j], acc[i][j]);
        }
        __syncthreads();
    }

    #pragma unroll
    for (int i = 0; i < 4; ++i) {
        int gm = m0 + ty * 4 + i;
        if (gm >= M) continue;
        float bi = (MODE == 2) ? bias[gm] : 0.0f;
        #pragma unroll
        for (int j = 0; j < 4; ++j) {
            int gn = n0 + tx * 4 + j;
            if (gn >= N) continue;
            float v = acc[i][j];
            if (MODE == 1) v = v * (1.0f / (1.0f + __expf(-v)));
            if (MODE == 2) {
                v += bi;
                v = (v > 15.0f) ? v : log1pf(__expf(v));
            }
            C[(long)gm * ldc + gn] = v;
        }
    }
}

// ---------------------------------------------------------------------------
// Depthwise causal conv (width 4) + bias + SiLU on TRANSPOSED x [1280][4096].
// ---------------------------------------------------------------------------
__global__ __launch_bounds__(256) void conv_silu_kernel(
    const float* __restrict__ xT, const float* __restrict__ cw,
    const float* __restrict__ cb, float* __restrict__ uT)
{
    int idx = blockIdx.x * 256 + threadIdx.x;      // d*4096 + bs
    if (idx >= D_INNER * M_TOTAL) return;
    int bs = idx & (M_TOTAL - 1);
    int d  = idx >> 12;
    int s  = bs & (SEQ - 1);

    const float* xr = xT + idx;
    float acc = cb[d];
    #pragma unroll
    for (int k = 0; k < D_CONV; ++k) {
        int off = k - (D_CONV - 1);                // -3..0
        if (s + off >= 0)
            acc = fmaf(xr[off], cw[d * D_CONV + k], acc);
    }
    uT[idx] = acc * (1.0f / (1.0f + __expf(-acc)));
}

// ---------------------------------------------------------------------------
// Selective scan v4: DPP-based wave reduction (VALU pipe, no LDS ops).
// ---------------------------------------------------------------------------
#define PF 8

#define DPP_ADD(X_, CTRL_) {                                                 \
        int t_ = __builtin_amdgcn_update_dpp(                                \
            0, __builtin_bit_cast(int, X_), (CTRL_), 0xf, 0xf, true);        \
        X_ += __builtin_bit_cast(float, t_);                                 \
    }

__global__ __launch_bounds__(64) void scan_kernel(
    const float* __restrict__ gT,      // silu(z)          [1280][4096]
    const float* __restrict__ xdbl,    // B/C at [bs*108 + 40(+34) + n]
    const float* __restrict__ spT,     // softplus(dt+bias)[1280][4096]
    const float* __restrict__ A_log,
    const float* __restrict__ D_skip,
    float* __restrict__ uT)            // in: u, out: y*g (in-place)
{
    const int wave = blockIdx.x;
    const int lane = threadIdx.x;      // 0..63
    const int b = wave / D_INNER;
    const int d = wave % D_INNER;
    const bool act = lane < D_STATE;

    const float A_n = act ? -__expf(A_log[d * D_STATE + lane]) : 0.0f;
    const float Dd  = D_skip[d];

    const long base = (long)d * M_TOTAL + (long)b * SEQ;
    const float* sp_p = spT + base;
    const float* g_p  = gT  + base;
    float*       u_p  = uT  + base;
    const float* bc_p = xdbl + (long)b * SEQ * XDBL_W;

    float h = 0.0f;

    float aSP[PF], aU[PF], aG[PF], aB[PF], aC[PF];
    float bSP[PF], bU[PF], bG[PF], bB[PF], bC[PF];

#define LOADS(SP_, U_, G_, B_, C_, T_) {                                     \
        int tt = (T_); tt = (tt < SEQ) ? tt : (SEQ - 1);                     \
        SP_ = sp_p[tt];                                                      \
        U_  = u_p [tt];                                                      \
        G_  = g_p [tt];                                                      \
        const float* bcq = bc_p + (long)tt * XDBL_W + DT_RANK + lane;        \
        B_ = act ? bcq[0]       : 0.0f;                                      \
        C_ = act ? bcq[D_STATE] : 0.0f;                                      \
    }

#define STEP(SP_, U_, G_, B_, C_, T_) {                                      \
        float dA = __expf(SP_ * A_n);                                        \
        h = fmaf(dA, h, (SP_ * U_) * B_);                                    \
        float pp = h * C_;                                                   \
        DPP_ADD(pp, 0x111);   /* row_shr:1  */                               \
        DPP_ADD(pp, 0x112);   /* row_shr:2  */                               \
        DPP_ADD(pp, 0x114);   /* row_shr:4  */                               \
        DPP_ADD(pp, 0x118);   /* row_shr:8  */                               \
        DPP_ADD(pp, 0x142);   /* row_bcast:15 */                             \
        DPP_ADD(pp, 0x143);   /* row_bcast:31 */                             \
        if (lane == 63) {                                                    \
            float y = fmaf(U_, Dd, pp);                                      \
            u_p[T_] = y * G_;                                                \
        }                                                                    \
    }

    #pragma unroll
    for (int i = 0; i < PF; ++i) LOADS(aSP[i], aU[i], aG[i], aB[i], aC[i], i);

    for (int t0 = 0; t0 < SEQ; t0 += 2 * PF) {
        #pragma unroll
        for (int i = 0; i < PF; ++i)
            LOADS(bSP[i], bU[i], bG[i], bB[i], bC[i], t0 + PF + i);
        #pragma unroll
        for (int i = 0; i < PF; ++i)
            STEP(aSP[i], aU[i], aG[i], aB[i], aC[i], t0 + i);
        #pragma unroll
        for (int i = 0; i < PF; ++i)
            LOADS(aSP[i], aU[i], aG[i], aB[i], aC[i], t0 + 2 * PF + i);
        #pragma unroll
        for (int i = 0; i < PF; ++i)
            STEP(bSP[i], bU[i], bG[i], bB[i], bC[i], t0 + PF + i);
    }
#undef LOADS
#undef STEP
}

// ---------------------------------------------------------------------------
extern "C" void kernel_launch(void* const* d_in, const int* in_sizes, int n_in,
                              void* d_out, int out_size, void* d_ws, size_t ws_size,
                              hipStream_t stream)
{
    const float* hs      = (const float*)d_in[0];
    const float* W_in    = (const float*)d_in[1];
    const float* conv_w  = (const float*)d_in[2];
    const float* conv_b  = (const float*)d_in[3];
    const float* W_x     = (const float*)d_in[4];
    const float* W_dt    = (const float*)d_in[5];
    const float* dt_bias = (const float*)d_in[6];
    const float* A_log   = (const float*)d_in[7];
    const float* D_skip  = (const float*)d_in[8];
    const float* W_out   = (const float*)d_in[9];
    float* out = (float*)d_out;

    float* ws   = (float*)d_ws;
    float* xT   = ws;                                        // 1280 x 4096
    float* gT   = xT   + (size_t)D_INNER * M_TOTAL;          // 1280 x 4096
    float* uT   = gT   + (size_t)D_INNER * M_TOTAL;          // 1280 x 4096 (u, then y)
    float* xdbl = uT   + (size_t)D_INNER * M_TOTAL;          // 4096 x 108
    float* spT  = xdbl + (size_t)M_TOTAL * XDBL_W;           // 1280 x 4096

    dim3 blk(256);

    // 1a) x_T = W_in[:1280] @ hs^T        [1280][4096]
    gemm128<0, 0, 128><<<dim3(M_TOTAL / 128, D_INNER / 128), blk, 0, stream>>>(
        W_in, hs, xT, D_INNER, M_TOTAL, D_MODEL, D_MODEL, D_MODEL, M_TOTAL, nullptr);

    // 1b) g_T = silu(W_in[1280:] @ hs^T)  [1280][4096]
    gemm128<0, 1, 128><<<dim3(M_TOTAL / 128, D_INNER / 128), blk, 0, stream>>>(
        W_in + (size_t)D_INNER * D_MODEL, hs, gT, D_INNER, M_TOTAL, D_MODEL,
        D_MODEL, D_MODEL, M_TOTAL, nullptr);

    // 2) u_T = silu(dwconv(x_T) + cb)     [1280][4096]
    conv_silu_kernel<<<(D_INNER * M_TOTAL + 255) / 256, blk, 0, stream>>>(
        xT, conv_w, conv_b, uT);

    // 3) x_dbl = u @ W_x^T                [4096][108]   (A = u_T, K-major)
    gemm_tn<1, 0><<<dim3((XDBL_W + BN - 1) / BN, M_TOTAL / BM), blk, 0, stream>>>(
        uT, W_x, xdbl, M_TOTAL, XDBL_W, D_INNER, M_TOTAL, D_INNER, XDBL_W, nullptr);

    // 4) sp_T = softplus(W_dt @ dt_raw^T + bias)  [1280][4096]
    gemm128<0, 2, 128><<<dim3(M_TOTAL / 128, D_INNER / 128), blk, 0, stream>>>(
        W_dt, xdbl, spT, D_INNER, M_TOTAL, DT_RANK, DT_RANK, XDBL_W, M_TOTAL,
        dt_bias);

    // 5) selective scan (fused D-skip + pre-gated z); y overwrites u_T.
    scan_kernel<<<BATCH * D_INNER, 64, 0, stream>>>(
        gT, xdbl, spT, A_log, D_skip, uT);

    // 6) out = y @ W_out^T                [4096][640]   (A = y_T, K-major)
    gemm128<1, 0, 64><<<dim3(D_MODEL / 64, M_TOTAL / 128), blk, 0, stream>>>(
        uT, W_out, out, M_TOTAL, D_MODEL, D_INNER, M_TOTAL, D_INNER, D_MODEL,
        nullptr);
}

// Round 9
// 884.637 us; speedup vs baseline: 1.1860x; 1.1860x over previous
//
#include <hip/hip_runtime.h>
#include <hip/hip_bf16.h>

#define D_MODEL   640
#define D_INNER   1280
#define D_STATE   34
#define D_CONV    4
#define DT_RANK   40
#define BATCH     2
#define SEQ       2048
#define XDBL_W    (DT_RANK + 2 * D_STATE)   // 108
#define M_TOTAL   (BATCH * SEQ)             // 4096

typedef __attribute__((ext_vector_type(8))) short short8v;   // bf16x8 (4 VGPR)
typedef __attribute__((ext_vector_type(4))) short short4v;   // bf16x4
typedef __attribute__((ext_vector_type(4))) float f32x4;     // MFMA acc

// Split f32 into bf16 hi (truncation) + bf16 lo (RNE of residual).
// x ~= hi + lo with relative error ~2^-16 (lo*lo term dropped in 3-term MFMA).
__device__ __forceinline__ void split_bf16(float x, short& hi, short& lo) {
    unsigned u  = __builtin_bit_cast(unsigned, x);
    unsigned uh = u & 0xFFFF0000u;
    hi = (short)(uh >> 16);
    float r = x - __builtin_bit_cast(float, uh);   // exact
    unsigned v = __builtin_bit_cast(unsigned, r);
    v += 0x7FFFu + ((v >> 16) & 1u);               // RNE to bf16
    lo = (short)(v >> 16);
}

__device__ __forceinline__ void split4(const float4& v, short4v& h, short4v& l) {
    float xs[4] = {v.x, v.y, v.z, v.w};
    #pragma unroll
    for (int j = 0; j < 4; ++j) { short hh, ll; split_bf16(xs[j], hh, ll); h[j] = hh; l[j] = ll; }
}

// ---------------------------------------------------------------------------
// Split-bf16 MFMA GEMM: C[M,N] = A[M,K] . B[N,K]^T  (fp32 in/out, ~fp32 acc).
// 128x128 tile, 256 threads (4 waves, 64x64 each), BK=32, mfma_f32_16x16x32_bf16.
// 3 MFMAs per fragment pair: hi*hi + hi*lo + lo*hi.
// M,N multiples of 128; K multiple of 32 (all launches satisfy this).
// MODE: 0 = none, 1 = silu(v)
// ---------------------------------------------------------------------------
template<int MODE>
__global__ __launch_bounds__(256) void gemm_mfma(
    const float* __restrict__ A, const float* __restrict__ B,
    float* __restrict__ C, int M, int N, int K, int lda, int ldb, int ldc)
{
    constexpr int BMt = 128, BNt = 128, BKt = 32;
    constexpr int LDT = 40;                        // LDS row stride in shorts (80B: pad vs 64B kills 8-way conflicts)
    __shared__ short Ahi[BMt * LDT], Alo[BMt * LDT];
    __shared__ short Bhi[BNt * LDT], Blo[BNt * LDT];

    const int tid  = threadIdx.x;
    const long m0  = (long)blockIdx.y * BMt;
    const long n0  = (long)blockIdx.x * BNt;
    const int wid  = tid >> 6, lane = tid & 63;
    const int wr   = (wid >> 1) * 64;              // wave row offset in tile
    const int wc   = (wid & 1) * 64;               // wave col offset in tile
    const int lrow = lane & 15;                    // A-row / B-col within fragment
    const int lkb  = lane >> 4;                    // k-block 0..3

    f32x4 acc[4][4] = {};

    for (int k0 = 0; k0 < K; k0 += BKt) {
        __syncthreads();                           // prev iter's frag reads done
        // ---- stage A/B 128x32 f32 -> bf16 hi/lo tiles (4 float4 each per thread)
        #pragma unroll
        for (int q = 0; q < 4; ++q) {
            int flat = tid + q * 256;              // 0..1023
            int r  = flat >> 3;                    // tile row 0..127
            int f4 = (flat & 7) << 2;              // k offset 0,4,...,28
            float4 va = *reinterpret_cast<const float4*>(&A[(m0 + r) * lda + k0 + f4]);
            float4 vb = *reinterpret_cast<const float4*>(&B[(n0 + r) * ldb + k0 + f4]);
            short4v ah, al, bh, bl;
            split4(va, ah, al);
            split4(vb, bh, bl);
            *reinterpret_cast<short4v*>(&Ahi[r * LDT + f4]) = ah;
            *reinterpret_cast<short4v*>(&Alo[r * LDT + f4]) = al;
            *reinterpret_cast<short4v*>(&Bhi[r * LDT + f4]) = bh;
            *reinterpret_cast<short4v*>(&Blo[r * LDT + f4]) = bl;
        }
        __syncthreads();

        // ---- fragments: a: lane holds A[lrow][lkb*8 + j]; b: B^T[lrow(col)][lkb*8 + j]
        short8v a_hi[4], a_lo[4], b_hi[4], b_lo[4];
        #pragma unroll
        for (int i = 0; i < 4; ++i) {
            int ar = (wr + i * 16 + lrow) * LDT + lkb * 8;
            int br = (wc + i * 16 + lrow) * LDT + lkb * 8;
            a_hi[i] = *reinterpret_cast<const short8v*>(&Ahi[ar]);
            a_lo[i] = *reinterpret_cast<const short8v*>(&Alo[ar]);
            b_hi[i] = *reinterpret_cast<const short8v*>(&Bhi[br]);
            b_lo[i] = *reinterpret_cast<const short8v*>(&Blo[br]);
        }
        #pragma unroll
        for (int i = 0; i < 4; ++i)
            #pragma unroll
            for (int j = 0; j < 4; ++j) {
                acc[i][j] = __builtin_amdgcn_mfma_f32_16x16x32_bf16(a_hi[i], b_hi[j], acc[i][j], 0, 0, 0);
                acc[i][j] = __builtin_amdgcn_mfma_f32_16x16x32_bf16(a_hi[i], b_lo[j], acc[i][j], 0, 0, 0);
                acc[i][j] = __builtin_amdgcn_mfma_f32_16x16x32_bf16(a_lo[i], b_hi[j], acc[i][j], 0, 0, 0);
            }
    }

    // ---- epilogue: D lane mapping col=lane&15, row=(lane>>4)*4+r (m89/m91)
    #pragma unroll
    for (int i = 0; i < 4; ++i) {
        long grow0 = m0 + wr + i * 16 + lkb * 4;
        #pragma unroll
        for (int j = 0; j < 4; ++j) {
            long gcol = n0 + wc + j * 16 + lrow;
            #pragma unroll
            for (int r = 0; r < 4; ++r) {
                float v = acc[i][j][r];
                if (MODE == 1) v = v * (1.0f / (1.0f + __expf(-v)));
                C[(grow0 + r) * ldc + gcol] = v;
            }
        }
    }
}

// ---------------------------------------------------------------------------
// Small f32 GEMM (thin x_dbl projection N=108, and dt projection K=40).
// C[M,N] = A.B^T with A [M,K] (LAYA=0) or [K,M] (LAYA=1); B [N,K].
// MODE: 0 = none, 2 = softplus(v + bias[gm])
// ---------------------------------------------------------------------------
#define BM 64
#define BN 64
#define BK 16

template<int LAYA, int MODE>
__global__ __launch_bounds__(256) void gemm_tn(
    const float* __restrict__ A, const float* __restrict__ B,
    float* __restrict__ C, int M, int N, int K, int lda, int ldb, int ldc,
    const float* __restrict__ bias)
{
    __shared__ float As[BK][BM + 4];
    __shared__ float Bs[BK][BN + 4];

    const int tid = threadIdx.x;
    const int m0 = blockIdx.y * BM;
    const int n0 = blockIdx.x * BN;
    const int tx = tid & 15;
    const int ty = tid >> 4;

    float acc[4][4] = {};

    for (int k0 = 0; k0 < K; k0 += BK) {
        #pragma unroll
        for (int i = 0; i < 4; ++i) {
            int idx = tid + i * 256;
            if (LAYA == 0) {
                int r = idx >> 4;
                int c = idx & 15;
                As[c][r] = (m0 + r < M && k0 + c < K)
                         ? A[(long)(m0 + r) * lda + (k0 + c)] : 0.0f;
            } else {
                int c = idx >> 6;
                int r = idx & 63;
                As[c][r] = (m0 + r < M && k0 + c < K)
                         ? A[(long)(k0 + c) * lda + (m0 + r)] : 0.0f;
            }
            int rb = idx >> 4;
            int cb = idx & 15;
            Bs[cb][rb] = (n0 + rb < N && k0 + cb < K)
                       ? B[(long)(n0 + rb) * ldb + (k0 + cb)] : 0.0f;
        }
        __syncthreads();

        #pragma unroll
        for (int k = 0; k < BK; ++k) {
            const float4 a4 = *reinterpret_cast<const float4*>(&As[k][ty * 4]);
            const float4 b4 = *reinterpret_cast<const float4*>(&Bs[k][tx * 4]);
            const float a_[4] = {a4.x, a4.y, a4.z, a4.w};
            const float b_[4] = {b4.x, b4.y, b4.z, b4.w};
            #pragma unroll
            for (int i = 0; i < 4; ++i)
                #pragma unroll
                for (int j = 0; j < 4; ++j)
                    acc[i][j] = fmaf(a_[i], b_[j], acc[i][j]);
        }
        __syncthreads();
    }

    #pragma unroll
    for (int i = 0; i < 4; ++i) {
        int gm = m0 + ty * 4 + i;
        if (gm >= M) continue;
        float bi = (MODE == 2) ? bias[gm] : 0.0f;
        #pragma unroll
        for (int j = 0; j < 4; ++j) {
            int gn = n0 + tx * 4 + j;
            if (gn >= N) continue;
            float v = acc[i][j];
            if (MODE == 2) {
                v += bi;
                v = (v > 15.0f) ? v : log1pf(__expf(v));   // softplus
            }
            C[(long)gm * ldc + gn] = v;
        }
    }
}

// ---------------------------------------------------------------------------
// Depthwise causal conv (width 4) + bias + SiLU on TRANSPOSED x [1280][4096].
// ---------------------------------------------------------------------------
__global__ __launch_bounds__(256) void conv_silu_kernel(
    const float* __restrict__ xT, const float* __restrict__ cw,
    const float* __restrict__ cb, float* __restrict__ uT)
{
    int idx = blockIdx.x * 256 + threadIdx.x;      // d*4096 + bs
    if (idx >= D_INNER * M_TOTAL) return;
    int bs = idx & (M_TOTAL - 1);
    int d  = idx >> 12;
    int s  = bs & (SEQ - 1);

    const float* xr = xT + idx;
    float acc = cb[d];
    #pragma unroll
    for (int k = 0; k < D_CONV; ++k) {
        int off = k - (D_CONV - 1);                // -3..0
        if (s + off >= 0)
            acc = fmaf(xr[off], cw[d * D_CONV + k], acc);
    }
    uT[idx] = acc * (1.0f / (1.0f + __expf(-acc)));
}

// ---------------------------------------------------------------------------
// Selective scan v5: DPP wave reduction; y now written to yN [4096][1280]
// (row-major in (bs, d)) so the out-projection can consume it M-major via MFMA.
// ---------------------------------------------------------------------------
#define PF 8

#define DPP_ADD(X_, CTRL_) {                                                 \
        int t_ = __builtin_amdgcn_update_dpp(                                \
            0, __builtin_bit_cast(int, X_), (CTRL_), 0xf, 0xf, true);        \
        X_ += __builtin_bit_cast(float, t_);                                 \
    }

__global__ __launch_bounds__(64) void scan_kernel(
    const float* __restrict__ gT,      // silu(z)          [1280][4096]
    const float* __restrict__ xdbl,    // B/C at [bs*108 + 40(+34) + n]
    const float* __restrict__ spT,     // softplus(dt+bias)[1280][4096]
    const float* __restrict__ A_log,
    const float* __restrict__ D_skip,
    const float* __restrict__ uT,      // u                [1280][4096]
    float* __restrict__ yN)            // out: y*g         [4096][1280]
{
    const int wave = blockIdx.x;
    const int lane = threadIdx.x;      // 0..63
    const int b = wave / D_INNER;
    const int d = wave % D_INNER;
    const bool act = lane < D_STATE;

    const float A_n = act ? -__expf(A_log[d * D_STATE + lane]) : 0.0f;
    const float Dd  = D_skip[d];

    const long base = (long)d * M_TOTAL + (long)b * SEQ;
    const float* sp_p = spT + base;
    const float* g_p  = gT  + base;
    const float* u_p  = uT  + base;
    float*       y_p  = yN  + (long)b * SEQ * D_INNER + d;
    const float* bc_p = xdbl + (long)b * SEQ * XDBL_W;

    float h = 0.0f;

    float aSP[PF], aU[PF], aG[PF], aB[PF], aC[PF];
    float bSP[PF], bU[PF], bG[PF], bB[PF], bC[PF];

#define LOADS(SP_, U_, G_, B_, C_, T_) {                                     \
        int tt = (T_); tt = (tt < SEQ) ? tt : (SEQ - 1);                     \
        SP_ = sp_p[tt];                                                      \
        U_  = u_p [tt];                                                      \
        G_  = g_p [tt];                                                      \
        const float* bcq = bc_p + (long)tt * XDBL_W + DT_RANK + lane;        \
        B_ = act ? bcq[0]       : 0.0f;                                      \
        C_ = act ? bcq[D_STATE] : 0.0f;                                      \
    }

#define STEP(SP_, U_, G_, B_, C_, T_) {                                      \
        float dA = __expf(SP_ * A_n);                                        \
        h = fmaf(dA, h, (SP_ * U_) * B_);                                    \
        float pp = h * C_;                                                   \
        DPP_ADD(pp, 0x111);   /* row_shr:1  */                               \
        DPP_ADD(pp, 0x112);   /* row_shr:2  */                               \
        DPP_ADD(pp, 0x114);   /* row_shr:4  */                               \
        DPP_ADD(pp, 0x118);   /* row_shr:8  */                               \
        DPP_ADD(pp, 0x142);   /* row_bcast:15 */                             \
        DPP_ADD(pp, 0x143);   /* row_bcast:31 */                             \
        if (lane == 63) {                                                    \
            float y = fmaf(U_, Dd, pp);                                      \
            y_p[(long)(T_) * D_INNER] = y * G_;                              \
        }                                                                    \
    }

    #pragma unroll
    for (int i = 0; i < PF; ++i) LOADS(aSP[i], aU[i], aG[i], aB[i], aC[i], i);

    for (int t0 = 0; t0 < SEQ; t0 += 2 * PF) {
        #pragma unroll
        for (int i = 0; i < PF; ++i)
            LOADS(bSP[i], bU[i], bG[i], bB[i], bC[i], t0 + PF + i);
        #pragma unroll
        for (int i = 0; i < PF; ++i)
            STEP(aSP[i], aU[i], aG[i], aB[i], aC[i], t0 + i);
        #pragma unroll
        for (int i = 0; i < PF; ++i)
            LOADS(aSP[i], aU[i], aG[i], aB[i], aC[i], t0 + 2 * PF + i);
        #pragma unroll
        for (int i = 0; i < PF; ++i)
            STEP(bSP[i], bU[i], bG[i], bB[i], bC[i], t0 + PF + i);
    }
#undef LOADS
#undef STEP
}

// ---------------------------------------------------------------------------
extern "C" void kernel_launch(void* const* d_in, const int* in_sizes, int n_in,
                              void* d_out, int out_size, void* d_ws, size_t ws_size,
                              hipStream_t stream)
{
    const float* hs      = (const float*)d_in[0];
    const float* W_in    = (const float*)d_in[1];
    const float* conv_w  = (const float*)d_in[2];
    const float* conv_b  = (const float*)d_in[3];
    const float* W_x     = (const float*)d_in[4];
    const float* W_dt    = (const float*)d_in[5];
    const float* dt_bias = (const float*)d_in[6];
    const float* A_log   = (const float*)d_in[7];
    const float* D_skip  = (const float*)d_in[8];
    const float* W_out   = (const float*)d_in[9];
    float* out = (float*)d_out;

    float* ws   = (float*)d_ws;
    float* xT   = ws;                                        // 1280 x 4096 (x; dead after conv -> reused as yN)
    float* gT   = xT   + (size_t)D_INNER * M_TOTAL;          // 1280 x 4096
    float* uT   = gT   + (size_t)D_INNER * M_TOTAL;          // 1280 x 4096
    float* xdbl = uT   + (size_t)D_INNER * M_TOTAL;          // 4096 x 108
    float* spT  = xdbl + (size_t)M_TOTAL * XDBL_W;           // 1280 x 4096
    float* yN   = xT;                                        // 4096 x 1280 (aliases dead xT)

    dim3 blk(256);

    // 1a) x_T = W_in[:1280] @ hs^T        [1280][4096]   (split-bf16 MFMA)
    gemm_mfma<0><<<dim3(M_TOTAL / 128, D_INNER / 128), blk, 0, stream>>>(
        W_in, hs, xT, D_INNER, M_TOTAL, D_MODEL, D_MODEL, D_MODEL, M_TOTAL);

    // 1b) g_T = silu(W_in[1280:] @ hs^T)  [1280][4096]   (split-bf16 MFMA)
    gemm_mfma<1><<<dim3(M_TOTAL / 128, D_INNER / 128), blk, 0, stream>>>(
        W_in + (size_t)D_INNER * D_MODEL, hs, gT, D_INNER, M_TOTAL, D_MODEL,
        D_MODEL, D_MODEL, M_TOTAL);

    // 2) u_T = silu(dwconv(x_T) + cb)     [1280][4096]
    conv_silu_kernel<<<(D_INNER * M_TOTAL + 255) / 256, blk, 0, stream>>>(
        xT, conv_w, conv_b, uT);

    // 3) x_dbl = u @ W_x^T                [4096][108]   (A = u_T, K-major, f32)
    gemm_tn<1, 0><<<dim3((XDBL_W + BN - 1) / BN, M_TOTAL / BM), blk, 0, stream>>>(
        uT, W_x, xdbl, M_TOTAL, XDBL_W, D_INNER, M_TOTAL, D_INNER, XDBL_W, nullptr);

    // 4) sp_T = softplus(W_dt @ dt_raw^T + bias)  [1280][4096]   (f32)
    gemm_tn<0, 2><<<dim3(M_TOTAL / BN, D_INNER / BM), blk, 0, stream>>>(
        W_dt, xdbl, spT, D_INNER, M_TOTAL, DT_RANK, DT_RANK, XDBL_W, M_TOTAL,
        dt_bias);

    // 5) selective scan; y written N-major into yN (= xT buffer, x is dead)
    scan_kernel<<<BATCH * D_INNER, 64, 0, stream>>>(
        gT, xdbl, spT, A_log, D_skip, uT, yN);

    // 6) out = y @ W_out^T                [4096][640]   (split-bf16 MFMA)
    gemm_mfma<0><<<dim3(D_MODEL / 128, M_TOTAL / 128), blk, 0, stream>>>(
        yN, W_out, out, M_TOTAL, D_MODEL, D_INNER, D_INNER, D_INNER, D_MODEL);
}

// Round 11
// 705.891 us; speedup vs baseline: 1.4864x; 1.2532x over previous
//
#include <hip/hip_runtime.h>
#include <hip/hip_bf16.h>

#define D_MODEL   640
#define D_INNER   1280
#define D_STATE   34
#define D_CONV    4
#define DT_RANK   40
#define BATCH     2
#define SEQ       2048
#define XDBL_W    (DT_RANK + 2 * D_STATE)   // 108
#define M_TOTAL   (BATCH * SEQ)             // 4096

typedef __attribute__((ext_vector_type(8))) short short8v;   // bf16x8 (4 VGPR)
typedef __attribute__((ext_vector_type(4))) short short4v;   // bf16x4
typedef __attribute__((ext_vector_type(4))) float f32x4;     // MFMA acc

// Split f32 into bf16 hi (truncation) + bf16 lo (RNE of residual).
__device__ __forceinline__ void split_bf16(float x, short& hi, short& lo) {
    unsigned u  = __builtin_bit_cast(unsigned, x);
    unsigned uh = u & 0xFFFF0000u;
    hi = (short)(uh >> 16);
    float r = x - __builtin_bit_cast(float, uh);   // exact
    unsigned v = __builtin_bit_cast(unsigned, r);
    v += 0x7FFFu + ((v >> 16) & 1u);               // RNE to bf16
    lo = (short)(v >> 16);
}

__device__ __forceinline__ void split4(const float4& v, short4v& h, short4v& l) {
    float xs[4] = {v.x, v.y, v.z, v.w};
    #pragma unroll
    for (int j = 0; j < 4; ++j) { short hh, ll; split_bf16(xs[j], hh, ll); h[j] = hh; l[j] = ll; }
}

// ---------------------------------------------------------------------------
// Split-bf16 MFMA GEMM: C[M,N] = A[M,K] . B[N,K]^T  (fp32 in/out, ~fp32 acc).
// 128x128 tile, 256 threads (4 waves, 64x64 each), BK=32, mfma_f32_16x16x32_bf16.
// 3 MFMAs per fragment pair: hi*hi + hi*lo + lo*hi.
// MODE: 0 = none, 1 = silu(v)
// ---------------------------------------------------------------------------
template<int MODE>
__global__ __launch_bounds__(256) void gemm_mfma(
    const float* __restrict__ A, const float* __restrict__ B,
    float* __restrict__ C, int M, int N, int K, int lda, int ldb, int ldc)
{
    constexpr int BMt = 128, BKt = 32;
    constexpr int LDT = 40;                        // LDS row stride in shorts
    __shared__ short Ahi[BMt * LDT], Alo[BMt * LDT];
    __shared__ short Bhi[BMt * LDT], Blo[BMt * LDT];

    const int tid  = threadIdx.x;
    const long m0  = (long)blockIdx.y * BMt;
    const long n0  = (long)blockIdx.x * BMt;
    const int wid  = tid >> 6, lane = tid & 63;
    const int wr   = (wid >> 1) * 64;              // wave row offset in tile
    const int wc   = (wid & 1) * 64;               // wave col offset in tile
    const int lrow = lane & 15;
    const int lkb  = lane >> 4;                    // k-block 0..3

    f32x4 acc[4][4] = {};

    for (int k0 = 0; k0 < K; k0 += BKt) {
        __syncthreads();
        #pragma unroll
        for (int q = 0; q < 4; ++q) {
            int flat = tid + q * 256;              // 0..1023
            int r  = flat >> 3;                    // tile row 0..127
            int f4 = (flat & 7) << 2;              // k offset 0,4,...,28
            float4 va = *reinterpret_cast<const float4*>(&A[(m0 + r) * lda + k0 + f4]);
            float4 vb = *reinterpret_cast<const float4*>(&B[(n0 + r) * ldb + k0 + f4]);
            short4v ah, al, bh, bl;
            split4(va, ah, al);
            split4(vb, bh, bl);
            *reinterpret_cast<short4v*>(&Ahi[r * LDT + f4]) = ah;
            *reinterpret_cast<short4v*>(&Alo[r * LDT + f4]) = al;
            *reinterpret_cast<short4v*>(&Bhi[r * LDT + f4]) = bh;
            *reinterpret_cast<short4v*>(&Blo[r * LDT + f4]) = bl;
        }
        __syncthreads();

        short8v a_hi[4], a_lo[4], b_hi[4], b_lo[4];
        #pragma unroll
        for (int i = 0; i < 4; ++i) {
            int ar = (wr + i * 16 + lrow) * LDT + lkb * 8;
            int br = (wc + i * 16 + lrow) * LDT + lkb * 8;
            a_hi[i] = *reinterpret_cast<const short8v*>(&Ahi[ar]);
            a_lo[i] = *reinterpret_cast<const short8v*>(&Alo[ar]);
            b_hi[i] = *reinterpret_cast<const short8v*>(&Bhi[br]);
            b_lo[i] = *reinterpret_cast<const short8v*>(&Blo[br]);
        }
        #pragma unroll
        for (int i = 0; i < 4; ++i)
            #pragma unroll
            for (int j = 0; j < 4; ++j) {
                acc[i][j] = __builtin_amdgcn_mfma_f32_16x16x32_bf16(a_hi[i], b_hi[j], acc[i][j], 0, 0, 0);
                acc[i][j] = __builtin_amdgcn_mfma_f32_16x16x32_bf16(a_hi[i], b_lo[j], acc[i][j], 0, 0, 0);
                acc[i][j] = __builtin_amdgcn_mfma_f32_16x16x32_bf16(a_lo[i], b_hi[j], acc[i][j], 0, 0, 0);
            }
    }

    // D lane mapping: col = lane&15, row = (lane>>4)*4 + r   (m89/m91)
    #pragma unroll
    for (int i = 0; i < 4; ++i) {
        long grow0 = m0 + wr + i * 16 + lkb * 4;
        #pragma unroll
        for (int j = 0; j < 4; ++j) {
            long gcol = n0 + wc + j * 16 + lrow;
            #pragma unroll
            for (int r = 0; r < 4; ++r) {
                float v = acc[i][j][r];
                if (MODE == 1) v = v * (1.0f / (1.0f + __expf(-v)));
                C[(grow0 + r) * ldc + gcol] = v;
            }
        }
    }
}

// ---------------------------------------------------------------------------
// Small f32 GEMM (thin x_dbl projection N=108, and dt projection K=40).
// ---------------------------------------------------------------------------
#define BM 64
#define BN 64
#define BK 16

template<int LAYA, int MODE>
__global__ __launch_bounds__(256) void gemm_tn(
    const float* __restrict__ A, const float* __restrict__ B,
    float* __restrict__ C, int M, int N, int K, int lda, int ldb, int ldc,
    const float* __restrict__ bias)
{
    __shared__ float As[BK][BM + 4];
    __shared__ float Bs[BK][BN + 4];

    const int tid = threadIdx.x;
    const int m0 = blockIdx.y * BM;
    const int n0 = blockIdx.x * BN;
    const int tx = tid & 15;
    const int ty = tid >> 4;

    float acc[4][4] = {};

    for (int k0 = 0; k0 < K; k0 += BK) {
        #pragma unroll
        for (int i = 0; i < 4; ++i) {
            int idx = tid + i * 256;
            if (LAYA == 0) {
                int r = idx >> 4;
                int c = idx & 15;
                As[c][r] = (m0 + r < M && k0 + c < K)
                         ? A[(long)(m0 + r) * lda + (k0 + c)] : 0.0f;
            } else {
                int c = idx >> 6;
                int r = idx & 63;
                As[c][r] = (m0 + r < M && k0 + c < K)
                         ? A[(long)(k0 + c) * lda + (m0 + r)] : 0.0f;
            }
            int rb = idx >> 4;
            int cb = idx & 15;
            Bs[cb][rb] = (n0 + rb < N && k0 + cb < K)
                       ? B[(long)(n0 + rb) * ldb + (k0 + cb)] : 0.0f;
        }
        __syncthreads();

        #pragma unroll
        for (int k = 0; k < BK; ++k) {
            const float4 a4 = *reinterpret_cast<const float4*>(&As[k][ty * 4]);
            const float4 b4 = *reinterpret_cast<const float4*>(&Bs[k][tx * 4]);
            const float a_[4] = {a4.x, a4.y, a4.z, a4.w};
            const float b_[4] = {b4.x, b4.y, b4.z, b4.w};
            #pragma unroll
            for (int i = 0; i < 4; ++i)
                #pragma unroll
                for (int j = 0; j < 4; ++j)
                    acc[i][j] = fmaf(a_[i], b_[j], acc[i][j]);
        }
        __syncthreads();
    }

    #pragma unroll
    for (int i = 0; i < 4; ++i) {
        int gm = m0 + ty * 4 + i;
        if (gm >= M) continue;
        float bi = (MODE == 2) ? bias[gm] : 0.0f;
        #pragma unroll
        for (int j = 0; j < 4; ++j) {
            int gn = n0 + tx * 4 + j;
            if (gn >= N) continue;
            float v = acc[i][j];
            if (MODE == 2) {
                v += bi;
                v = (v > 15.0f) ? v : log1pf(__expf(v));   // softplus
            }
            C[(long)gm * ldc + gn] = v;
        }
    }
}

// ---------------------------------------------------------------------------
// Depthwise causal conv (width 4) + bias + SiLU on TRANSPOSED x [1280][4096].
// ---------------------------------------------------------------------------
__global__ __launch_bounds__(256) void conv_silu_kernel(
    const float* __restrict__ xT, const float* __restrict__ cw,
    const float* __restrict__ cb, float* __restrict__ uT)
{
    int idx = blockIdx.x * 256 + threadIdx.x;      // d*4096 + bs
    if (idx >= D_INNER * M_TOTAL) return;
    int bs = idx & (M_TOTAL - 1);
    int d  = idx >> 12;
    int s  = bs & (SEQ - 1);

    const float* xr = xT + idx;
    float acc = cb[d];
    #pragma unroll
    for (int k = 0; k < D_CONV; ++k) {
        int off = k - (D_CONV - 1);                // -3..0
        if (s + off >= 0)
            acc = fmaf(xr[off], cw[d * D_CONV + k], acc);
    }
    uT[idx] = acc * (1.0f / (1.0f + __expf(-acc)));
}

// ---------------------------------------------------------------------------
// LDS-tiled transpose: in [1280][4096] -> out [4096][1280]. 32x32 tiles.
// Both global read and write fully coalesced.
// ---------------------------------------------------------------------------
__global__ __launch_bounds__(256) void transpose_kernel(
    const float* __restrict__ in, float* __restrict__ out)
{
    __shared__ float tile[32][33];
    const int tx = threadIdx.x & 31;
    const int ty = threadIdx.x >> 5;               // 0..7
    const int t0 = blockIdx.x * 32;                // col (seq) tile
    const int d0 = blockIdx.y * 32;                // row (channel) tile

    #pragma unroll
    for (int i = 0; i < 32; i += 8)
        tile[ty + i][tx] = in[(long)(d0 + ty + i) * M_TOTAL + t0 + tx];
    __syncthreads();
    #pragma unroll
    for (int i = 0; i < 32; i += 8)
        out[(long)(t0 + ty + i) * D_INNER + d0 + tx] = tile[tx][ty + i];
}

// ---------------------------------------------------------------------------
// Selective scan v6 (= round-4 v4): DPP wave reduction, in-place y over uT
// (contiguous per-wave reads AND writes; WRITE_SIZE ~20 MB).
// ---------------------------------------------------------------------------
#define PF 8

#define DPP_ADD(X_, CTRL_) {                                                 \
        int t_ = __builtin_amdgcn_update_dpp(                                \
            0, __builtin_bit_cast(int, X_), (CTRL_), 0xf, 0xf, true);        \
        X_ += __builtin_bit_cast(float, t_);                                 \
    }

__global__ __launch_bounds__(64) void scan_kernel(
    const float* __restrict__ gT,      // silu(z)          [1280][4096]
    const float* __restrict__ xdbl,    // B/C at [bs*108 + 40(+34) + n]
    const float* __restrict__ spT,     // softplus(dt+bias)[1280][4096]
    const float* __restrict__ A_log,
    const float* __restrict__ D_skip,
    float* __restrict__ uT)            // in: u, out: y*g (in-place)
{
    const int wave = blockIdx.x;
    const int lane = threadIdx.x;      // 0..63
    const int b = wave / D_INNER;
    const int d = wave % D_INNER;
    const bool act = lane < D_STATE;

    const float A_n = act ? -__expf(A_log[d * D_STATE + lane]) : 0.0f;
    const float Dd  = D_skip[d];

    const long base = (long)d * M_TOTAL + (long)b * SEQ;
    const float* sp_p = spT + base;
    const float* g_p  = gT  + base;
    float*       u_p  = uT  + base;
    const float* bc_p = xdbl + (long)b * SEQ * XDBL_W;

    float h = 0.0f;

    float aSP[PF], aU[PF], aG[PF], aB[PF], aC[PF];
    float bSP[PF], bU[PF], bG[PF], bB[PF], bC[PF];

#define LOADS(SP_, U_, G_, B_, C_, T_) {                                     \
        int tt = (T_); tt = (tt < SEQ) ? tt : (SEQ - 1);                     \
        SP_ = sp_p[tt];                                                      \
        U_  = u_p [tt];                                                      \
        G_  = g_p [tt];                                                      \
        const float* bcq = bc_p + (long)tt * XDBL_W + DT_RANK + lane;        \
        B_ = act ? bcq[0]       : 0.0f;                                      \
        C_ = act ? bcq[D_STATE] : 0.0f;                                      \
    }

#define STEP(SP_, U_, G_, B_, C_, T_) {                                      \
        float dA = __expf(SP_ * A_n);                                        \
        h = fmaf(dA, h, (SP_ * U_) * B_);                                    \
        float pp = h * C_;                                                   \
        DPP_ADD(pp, 0x111);   /* row_shr:1  */                               \
        DPP_ADD(pp, 0x112);   /* row_shr:2  */                               \
        DPP_ADD(pp, 0x114);   /* row_shr:4  */                               \
        DPP_ADD(pp, 0x118);   /* row_shr:8  */                               \
        DPP_ADD(pp, 0x142);   /* row_bcast:15 */                             \
        DPP_ADD(pp, 0x143);   /* row_bcast:31 */                             \
        if (lane == 63) {                                                    \
            float y = fmaf(U_, Dd, pp);                                      \
            u_p[T_] = y * G_;                                                \
        }                                                                    \
    }

    #pragma unroll
    for (int i = 0; i < PF; ++i) LOADS(aSP[i], aU[i], aG[i], aB[i], aC[i], i);

    for (int t0 = 0; t0 < SEQ; t0 += 2 * PF) {
        #pragma unroll
        for (int i = 0; i < PF; ++i)
            LOADS(bSP[i], bU[i], bG[i], bB[i], bC[i], t0 + PF + i);
        #pragma unroll
        for (int i = 0; i < PF; ++i)
            STEP(aSP[i], aU[i], aG[i], aB[i], aC[i], t0 + i);
        #pragma unroll
        for (int i = 0; i < PF; ++i)
            LOADS(aSP[i], aU[i], aG[i], aB[i], aC[i], t0 + 2 * PF + i);
        #pragma unroll
        for (int i = 0; i < PF; ++i)
            STEP(bSP[i], bU[i], bG[i], bB[i], bC[i], t0 + PF + i);
    }
#undef LOADS
#undef STEP
}

// ---------------------------------------------------------------------------
extern "C" void kernel_launch(void* const* d_in, const int* in_sizes, int n_in,
                              void* d_out, int out_size, void* d_ws, size_t ws_size,
                              hipStream_t stream)
{
    const float* hs      = (const float*)d_in[0];
    const float* W_in    = (const float*)d_in[1];
    const float* conv_w  = (const float*)d_in[2];
    const float* conv_b  = (const float*)d_in[3];
    const float* W_x     = (const float*)d_in[4];
    const float* W_dt    = (const float*)d_in[5];
    const float* dt_bias = (const float*)d_in[6];
    const float* A_log   = (const float*)d_in[7];
    const float* D_skip  = (const float*)d_in[8];
    const float* W_out   = (const float*)d_in[9];
    float* out = (float*)d_out;

    float* ws   = (float*)d_ws;
    float* xT   = ws;                                        // 1280 x 4096 (x; dead after conv -> yN)
    float* gT   = xT   + (size_t)D_INNER * M_TOTAL;          // 1280 x 4096
    float* uT   = gT   + (size_t)D_INNER * M_TOTAL;          // 1280 x 4096 (u, then y in-place)
    float* xdbl = uT   + (size_t)D_INNER * M_TOTAL;          // 4096 x 108
    float* spT  = xdbl + (size_t)M_TOTAL * XDBL_W;           // 1280 x 4096
    float* yN   = xT;                                        // 4096 x 1280 (aliases dead xT)

    dim3 blk(256);

    // 1a) x_T = W_in[:1280] @ hs^T        [1280][4096]   (split-bf16 MFMA)
    gemm_mfma<0><<<dim3(M_TOTAL / 128, D_INNER / 128), blk, 0, stream>>>(
        W_in, hs, xT, D_INNER, M_TOTAL, D_MODEL, D_MODEL, D_MODEL, M_TOTAL);

    // 1b) g_T = silu(W_in[1280:] @ hs^T)  [1280][4096]   (split-bf16 MFMA)
    gemm_mfma<1><<<dim3(M_TOTAL / 128, D_INNER / 128), blk, 0, stream>>>(
        W_in + (size_t)D_INNER * D_MODEL, hs, gT, D_INNER, M_TOTAL, D_MODEL,
        D_MODEL, D_MODEL, M_TOTAL);

    // 2) u_T = silu(dwconv(x_T) + cb)     [1280][4096]
    conv_silu_kernel<<<(D_INNER * M_TOTAL + 255) / 256, blk, 0, stream>>>(
        xT, conv_w, conv_b, uT);

    // 3) x_dbl = u @ W_x^T                [4096][108]   (A = u_T, K-major, f32)
    gemm_tn<1, 0><<<dim3((XDBL_W + BN - 1) / BN, M_TOTAL / BM), blk, 0, stream>>>(
        uT, W_x, xdbl, M_TOTAL, XDBL_W, D_INNER, M_TOTAL, D_INNER, XDBL_W, nullptr);

    // 4) sp_T = softplus(W_dt @ dt_raw^T + bias)  [1280][4096]   (f32)
    gemm_tn<0, 2><<<dim3(M_TOTAL / BN, D_INNER / BM), blk, 0, stream>>>(
        W_dt, xdbl, spT, D_INNER, M_TOTAL, DT_RANK, DT_RANK, XDBL_W, M_TOTAL,
        dt_bias);

    // 5) selective scan; y overwrites uT in place (contiguous writes)
    scan_kernel<<<BATCH * D_INNER, 64, 0, stream>>>(
        gT, xdbl, spT, A_log, D_skip, uT);

    // 5b) transpose y: uT [1280][4096] -> yN [4096][1280] (coalesced both sides)
    transpose_kernel<<<dim3(M_TOTAL / 32, D_INNER / 32), blk, 0, stream>>>(uT, yN);

    // 6) out = y @ W_out^T                [4096][640]   (split-bf16 MFMA)
    gemm_mfma<0><<<dim3(D_MODEL / 128, M_TOTAL / 128), blk, 0, stream>>>(
        yN, W_out, out, M_TOTAL, D_MODEL, D_INNER, D_INNER, D_INNER, D_MODEL);
}